// Round 2
// baseline (610.854 us; speedup 1.0000x reference)
//
#include <hip/hip_runtime.h>
#include <cstdint>

// TTLinear: y = x @ W^T + bias, W (4096x4096) reconstructed from TT cores,
// then a bf16 MFMA GEMM.
//
// R5: R4's 256x256/BK=32/4-deep-ring schedule was over-synchronized: 4
// barriers per tile forced all 8 waves into lockstep, serializing the
// ds_read section against the MFMA section (measured: tile time ~= LDS
// cycles + matrix cycles, i.e. the SUM not the MAX; MfmaUtil 46%). R5 keeps
// the ring + counted vmcnt(8) but drops to ONE barrier per tile -- the
// minimum the ring needs: staging into buffer sb only requires the end-of-
// tile-(t-1) barrier (sb last read in t-1), and reading tile t only requires
// every wave's vmcnt(8) + one barrier (all staging loads for t landed).
// Within a tile the compiler interleaves ds_reads with MFMAs via fine
// lgkmcnt, and the 2 waves/SIMD drift to overlap LDS and matrix pipes.
//
// ws layout: [0,64MiB) xb bf16, [64MiB,96MiB) Wbt bf16 (N x K), then C01 fp32.

typedef __bf16 bf16x8 __attribute__((ext_vector_type(8)));
typedef float f32x4 __attribute__((ext_vector_type(4)));
typedef unsigned short u16;
typedef u16 u16x8 __attribute__((ext_vector_type(8)));

__device__ __forceinline__ u16 f2bf(float f) {
    unsigned u = __builtin_bit_cast(unsigned, f);
    u += 0x7fffu + ((u >> 16) & 1u);   // round-to-nearest-even
    return (u16)(u >> 16);
}

// ---- kernel 1: x fp32 -> bf16 (8 elems/thread, 16B stores) ----
__global__ void k_cvt(const float* __restrict__ x, u16* __restrict__ xb) {
    long i = (long)blockIdx.x * blockDim.x + threadIdx.x;   // one per 8 floats
    const float4* p = (const float4*)x;
    float4 a = p[2 * i], b = p[2 * i + 1];
    u16x8 o;
    o[0] = f2bf(a.x); o[1] = f2bf(a.y); o[2] = f2bf(a.z); o[3] = f2bf(a.w);
    o[4] = f2bf(b.x); o[5] = f2bf(b.y); o[6] = f2bf(b.z); o[7] = f2bf(b.w);
    ((u16x8*)xb)[i] = o;
}

// ---- kernel 2: C01[o0][o1][i0][i1][b2] = sum_b1 core0[0,o0,i0,b1]*core1[b1,o1,i1,b2]
__global__ void k_c01(const float* __restrict__ c0, const float* __restrict__ c1,
                      float* __restrict__ c01) {
    int idx = blockIdx.x * 256 + threadIdx.x;   // 524288 total
    int b2 = idx & 7, i1 = (idx >> 3) & 15, i0 = (idx >> 7) & 15;
    int o1 = (idx >> 11) & 15, o0 = idx >> 15;
    float s = 0.f;
#pragma unroll
    for (int b1 = 0; b1 < 8; ++b1)
        s += c0[(o0 * 16 + i0) * 8 + b1] * c1[((b1 * 16 + o1) * 16 + i1) * 8 + b2];
    c01[idx] = s;
}

// ---- kernel 3: Wbt[o][i] bf16 (B^T layout, N x K); thread computes 8 consecutive i
__global__ void k_w(const float* __restrict__ c01, const float* __restrict__ c2,
                    u16* __restrict__ wbt) {
    int idx = blockIdx.x * 256 + threadIdx.x;   // 2,097,152 total
    int i2h = idx & 1;
    int i1 = (idx >> 1) & 15;
    int i0 = (idx >> 5) & 15;
    int o = idx >> 9;                            // 0..4095
    int o2 = o & 15, o1 = (o >> 4) & 15, o0 = o >> 8;
    const float* c = &c01[(((o0 * 16 + o1) * 16 + i0) * 16 + i1) * 8];
    float acc[8] = {0, 0, 0, 0, 0, 0, 0, 0};
#pragma unroll
    for (int b2 = 0; b2 < 8; ++b2) {
        float cv = c[b2];
        const float* cc = &c2[(b2 * 16 + o2) * 16 + i2h * 8];
#pragma unroll
        for (int j = 0; j < 8; ++j) acc[j] += cv * cc[j];
    }
    u16x8 ov;
#pragma unroll
    for (int j = 0; j < 8; ++j) ov[j] = f2bf(acc[j]);
    ((u16x8*)wbt)[(long)o * 512 + (i0 * 32 + i1 * 2 + i2h)] = ov;
}

// ---- kernel 4: GEMM. C[m][n] = sum_k A[m,k]*B[n,k] + bias[n] ----
#define BM 256
#define BN 256
#define BK 32
#define NBUF 4
#define TA (BM * BK)                 // 8192 u16 per A tile (16 KiB)
#define TB (BN * BK)
#define LDS_BYTES (NBUF * (TA + TB) * 2)   // 131072

static_assert(LDS_BYTES == 131072, "lds size");

__device__ __forceinline__ void gload_lds16(const void* g, void* l) {
    __builtin_amdgcn_global_load_lds(
        (const __attribute__((address_space(1))) unsigned*)g,
        (__attribute__((address_space(3))) unsigned*)l, 16, 0, 0);
}

__launch_bounds__(512, 2)
__global__ void k_gemm(const u16* __restrict__ A, const u16* __restrict__ B,
                       const float* __restrict__ bias, float* __restrict__ C,
                       int M, int N, int K) {
    extern __shared__ __align__(16) u16 lds[];
    u16* lA = lds;                       // NBUF * TA
    u16* lB = lds + NBUF * TA;           // NBUF * TB

    // XCD-aware swizzle: 512 blocks, 8 XCDs, 64 blocks per XCD chunk.
    const int wg = blockIdx.x;
    const int swz = (wg & 7) * 64 + (wg >> 3);
    const int bn = swz & 15, bm = swz >> 4;       // 16 N-blocks x 32 M-blocks
    const int m0 = bm * BM, n0 = bn * BN;

    const int t = threadIdx.x;
    const int wave = t >> 6, lane = t & 63;
    const int wm = wave >> 2, wn = wave & 3;      // 2 (M) x 4 (N) waves
    const int lr = lane & 15, quad = lane >> 4;

    // Staging: tile = 256 rows x 32 cols bf16 = 1024 16B-chunks. Thread loads
    // chunks ci = j*512+t (j=0,1). LDS is linear in ci; the GLOBAL chunk is
    // pre-swizzled: row r = ci>>2, slot = ci&3, global chunk = slot^((r>>1)&3).
    const u16* pa[2]; const u16* pb[2]; int lof[2];
#pragma unroll
    for (int j = 0; j < 2; ++j) {
        int ci = j * 512 + t;
        int r = ci >> 2;
        int c = (ci & 3) ^ ((r >> 1) & 3);
        pa[j] = &A[(long)(m0 + r) * K + c * 8];
        pb[j] = &B[(long)(n0 + r) * K + c * 8];
        lof[j] = ci * 8;                 // u16 units
    }

    // Fragment read offsets (u16 units), same swizzle on the read side.
    int offA[8], offB[4];
#pragma unroll
    for (int mi = 0; mi < 8; ++mi) {
        int r = wm * 128 + mi * 16 + lr;
        offA[mi] = r * BK + ((quad ^ ((r >> 1) & 3)) << 3);
    }
#pragma unroll
    for (int ni = 0; ni < 4; ++ni) {
        int r = wn * 64 + ni * 16 + lr;
        offB[ni] = r * BK + ((quad ^ ((r >> 1) & 3)) << 3);
    }

    f32x4 acc[8][4];
#pragma unroll
    for (int mi = 0; mi < 8; ++mi)
#pragma unroll
        for (int ni = 0; ni < 4; ++ni) acc[mi][ni] = 0.f;

    const int NT = K / BK;   // 128

    // Prologue: stage tiles 0,1,2 (12 loads); vmcnt(8) -> tile0 landed.
#pragma unroll
    for (int tt = 0; tt < 3; ++tt) {
#pragma unroll
        for (int j = 0; j < 2; ++j)
            gload_lds16(pa[j] + (long)tt * BK, lA + tt * TA + lof[j]);
#pragma unroll
        for (int j = 0; j < 2; ++j)
            gload_lds16(pb[j] + (long)tt * BK, lB + tt * TB + lof[j]);
    }
    asm volatile("s_waitcnt vmcnt(8)" ::: "memory");
    __builtin_amdgcn_s_barrier();

    // Main loop. Invariant entering tile t: tiles t+1,t+2 in flight (8 loads
    // outstanding), tile t landed. During tile t we issue tile t+3's 4 loads
    // into buffer (t+3)&3 (freed at end of tile t-1 -> race-free); the
    // end-of-tile vmcnt(8) retires tile t+1's loads. ONE barrier per tile;
    // within the tile, ds_reads and MFMAs interleave under compiler lgkmcnt
    // scheduling and the 2 waves/SIMD overlap LDS vs matrix pipes.
#pragma unroll 1
    for (int tb = 0; tb < NT; tb += 4) {
#pragma unroll
        for (int u = 0; u < 4; ++u) {
            const int tt = tb + u;
            const u16* aT = lA + u * TA;           // read buffer (tt & 3 == u)
            const u16* bT = lB + u * TB;
            const int sb = (u + 3) & 3;            // stage buffer
            const bool pre = (tt + 3 < NT);

            // stage tile t+3 (issue-early; lands ~2 tiles later)
            if (pre) {
#pragma unroll
                for (int j = 0; j < 2; ++j)
                    gload_lds16(pa[j] + (long)(tt + 3) * BK, lA + sb * TA + lof[j]);
#pragma unroll
                for (int j = 0; j < 2; ++j)
                    gload_lds16(pb[j] + (long)(tt + 3) * BK, lB + sb * TB + lof[j]);
            }

            // fragments + MFMA; no intra-tile barriers.
            bf16x8 bf[4], af[8];
#pragma unroll
            for (int ni = 0; ni < 4; ++ni) bf[ni] = *(const bf16x8*)&bT[offB[ni]];
#pragma unroll
            for (int mi = 0; mi < 8; ++mi) af[mi] = *(const bf16x8*)&aT[offA[mi]];
            __builtin_amdgcn_s_setprio(1);
#pragma unroll
            for (int mi = 0; mi < 8; ++mi)
#pragma unroll
                for (int ni = 0; ni < 4; ++ni)
                    acc[mi][ni] = __builtin_amdgcn_mfma_f32_16x16x32_bf16(
                        af[mi], bf[ni], acc[mi][ni], 0, 0, 0);
            __builtin_amdgcn_s_setprio(0);

            // end-of-tile: counted wait (tile t+1 landed), then barrier.
            if (pre)                 asm volatile("s_waitcnt vmcnt(8)" ::: "memory");
            else if (tt + 2 < NT)    asm volatile("s_waitcnt vmcnt(4)" ::: "memory");
            else if (tt + 1 < NT)    asm volatile("s_waitcnt vmcnt(0)" ::: "memory");
            __builtin_amdgcn_s_barrier();
        }
    }

    // Epilogue: D row = quad*4 + r (m), col = lr (n); add bias, store fp32.
#pragma unroll
    for (int ni = 0; ni < 4; ++ni) {
        int gn = n0 + wn * 64 + ni * 16 + lr;
        float bv = bias[gn];
#pragma unroll
        for (int mi = 0; mi < 8; ++mi) {
            int gm = m0 + wm * 128 + mi * 16 + quad * 4;
#pragma unroll
            for (int r = 0; r < 4; ++r)
                C[(long)(gm + r) * N + gn] = acc[mi][ni][r] + bv;
        }
    }
}

extern "C" void kernel_launch(void* const* d_in, const int* in_sizes, int n_in,
                              void* d_out, int out_size, void* d_ws, size_t ws_size,
                              hipStream_t stream) {
    const float* x = (const float*)d_in[0];
    const float* c0 = (const float*)d_in[1];
    const float* c1 = (const float*)d_in[2];
    const float* c2 = (const float*)d_in[3];
    const float* bias = (const float*)d_in[4];
    float* out = (float*)d_out;

    const int Mb = 8192, Nf = 4096, Kf = 4096;
    char* ws = (char*)d_ws;
    u16* xb = (u16*)ws;                                       // 67,108,864 B
    u16* wbt = (u16*)(ws + 67108864);                         // 33,554,432 B
    float* c01 = (float*)(ws + 67108864 + 33554432);          //  2,097,152 B

    // 128 KiB dynamic LDS (> 64 KiB static limit). Idempotent, capture-safe.
    hipFuncSetAttribute(reinterpret_cast<const void*>(k_gemm),
                        hipFuncAttributeMaxDynamicSharedMemorySize, LDS_BYTES);

    k_cvt<<<dim3((Mb * Kf / 8) / 256), 256, 0, stream>>>(x, xb);
    k_c01<<<dim3(2048), 256, 0, stream>>>(c0, c1, c01);
    k_w<<<dim3(8192), 256, 0, stream>>>(c01, c2, wbt);
    k_gemm<<<dim3((Mb / BM) * (Nf / BN)), dim3(512), LDS_BYTES, stream>>>(
        xb, wbt, bias, out, Mb, Nf, Kf);
}

// Round 4
// 464.458 us; speedup vs baseline: 1.3152x; 1.3152x over previous
//
#include <hip/hip_runtime.h>
#include <cstdint>

// TTLinear: y = x @ W^T + bias, W (4096x4096) reconstructed from TT cores,
// then a bf16 MFMA GEMM.
//
// R7 = R6 with the staging-half/read-phase mismatch FIXED. R6's race: A/B
// tiles were staged in tile-row halves (A0 = rows 0..127), but phase P1
// reads rows wm*128 + 0..63 -- wm=1 waves touched rows 128..191 before that
// half's vmcnt retirement (absmax 0.354). Fix: permute LDS row layout so
// staged half == read phase. A: lds_row = H*128 + wm*64 + o for global row
// wm*128 + H*64 + o. B: lds_row = G*128 + wn*32 + o for global row
// wn*64 + G*32 + o. global_load_lds sources are per-lane, so staging stays
// coalesced; LDS stays linear; XOR chunk swizzle unchanged (lds_row&7 ==
// lr&7 on reads). Schedule (m201 template): BK=64, 4 phases/K-tile, one
// C-quadrant (16 MFMA)/phase, B-halves in regs, 2 gload_lds/phase in order
// A0',B0',B1',A1', counted vmcnt(4) at ends of P1/P2/P4 (retires exactly
// the half needed next; never drains below 4 in steady state).
//
// ws layout: [0,64MiB) xb bf16, [64MiB,96MiB) Wbt bf16 (N x K), then C01 fp32.

typedef __bf16 bf16x8 __attribute__((ext_vector_type(8)));
typedef float f32x4 __attribute__((ext_vector_type(4)));
typedef unsigned short u16;
typedef u16 u16x8 __attribute__((ext_vector_type(8)));

__device__ __forceinline__ u16 f2bf(float f) {
    unsigned u = __builtin_bit_cast(unsigned, f);
    u += 0x7fffu + ((u >> 16) & 1u);   // round-to-nearest-even
    return (u16)(u >> 16);
}

// ---- kernel 1: x fp32 -> bf16 (8 elems/thread, 16B stores) ----
__global__ void k_cvt(const float* __restrict__ x, u16* __restrict__ xb) {
    long i = (long)blockIdx.x * blockDim.x + threadIdx.x;   // one per 8 floats
    const float4* p = (const float4*)x;
    float4 a = p[2 * i], b = p[2 * i + 1];
    u16x8 o;
    o[0] = f2bf(a.x); o[1] = f2bf(a.y); o[2] = f2bf(a.z); o[3] = f2bf(a.w);
    o[4] = f2bf(b.x); o[5] = f2bf(b.y); o[6] = f2bf(b.z); o[7] = f2bf(b.w);
    ((u16x8*)xb)[i] = o;
}

// ---- kernel 2: C01[o0][o1][i0][i1][b2] = sum_b1 core0[0,o0,i0,b1]*core1[b1,o1,i1,b2]
__global__ void k_c01(const float* __restrict__ c0, const float* __restrict__ c1,
                      float* __restrict__ c01) {
    int idx = blockIdx.x * 256 + threadIdx.x;   // 524288 total
    int b2 = idx & 7, i1 = (idx >> 3) & 15, i0 = (idx >> 7) & 15;
    int o1 = (idx >> 11) & 15, o0 = idx >> 15;
    float s = 0.f;
#pragma unroll
    for (int b1 = 0; b1 < 8; ++b1)
        s += c0[(o0 * 16 + i0) * 8 + b1] * c1[((b1 * 16 + o1) * 16 + i1) * 8 + b2];
    c01[idx] = s;
}

// ---- kernel 3: Wbt[o][i] bf16 (B^T layout, N x K); thread computes 8 consecutive i
__global__ void k_w(const float* __restrict__ c01, const float* __restrict__ c2,
                    u16* __restrict__ wbt) {
    int idx = blockIdx.x * 256 + threadIdx.x;   // 2,097,152 total
    int i2h = idx & 1;
    int i1 = (idx >> 1) & 15;
    int i0 = (idx >> 5) & 15;
    int o = idx >> 9;                            // 0..4095
    int o2 = o & 15, o1 = (o >> 4) & 15, o0 = o >> 8;
    const float* c = &c01[(((o0 * 16 + o1) * 16 + i0) * 16 + i1) * 8];
    float acc[8] = {0, 0, 0, 0, 0, 0, 0, 0};
#pragma unroll
    for (int b2 = 0; b2 < 8; ++b2) {
        float cv = c[b2];
        const float* cc = &c2[(b2 * 16 + o2) * 16 + i2h * 8];
#pragma unroll
        for (int j = 0; j < 8; ++j) acc[j] += cv * cc[j];
    }
    u16x8 ov;
#pragma unroll
    for (int j = 0; j < 8; ++j) ov[j] = f2bf(acc[j]);
    ((u16x8*)wbt)[(long)o * 512 + (i0 * 32 + i1 * 2 + i2h)] = ov;
}

// ---- kernel 4: GEMM. C[m][n] = sum_k A[m,k]*B[n,k] + bias[n] ----
#define BM 256
#define BN 256
#define BK 64
#define TILEU (BM * BK)                 // 16384 u16 = 32 KiB per operand buf
#define LDS_BYTES (4 * TILEU * 2)       // 2 bufs x (A+B) x 2B = 131072

static_assert(LDS_BYTES == 131072, "lds size");

__device__ __forceinline__ void gload_lds16(const void* g, void* l) {
    __builtin_amdgcn_global_load_lds(
        (const __attribute__((address_space(1))) unsigned*)g,
        (__attribute__((address_space(3))) unsigned*)l, 16, 0, 0);
}

#define VMW(N) asm volatile("s_waitcnt vmcnt(" #N ")" ::: "memory")
#define LGKM0  asm volatile("s_waitcnt lgkmcnt(0)" ::: "memory")
#define BAR()  __builtin_amdgcn_s_barrier()

// read A phase-half H (8 x ds_read_b128): lds rows H*128 + wm*64 + mi*16 + lr
#define READ_A(H) do { \
    _Pragma("unroll") for (int mi_ = 0; mi_ < 4; ++mi_) { \
        af[mi_ * 2 + 0] = *(const bf16x8*)&aT[arow + ((H) * 128 + mi_ * 16) * 64 + swz0]; \
        af[mi_ * 2 + 1] = *(const bf16x8*)&aT[arow + ((H) * 128 + mi_ * 16) * 64 + swz1]; \
    } } while (0)

// read B phase-half G (4 x ds_read_b128): lds rows G*128 + wn*32 + ni*16 + lr
#define READ_B(G, BF) do { \
    _Pragma("unroll") for (int ni_ = 0; ni_ < 2; ++ni_) { \
        BF[ni_ * 2 + 0] = *(const bf16x8*)&bT[brow + ((G) * 128 + ni_ * 16) * 64 + swz0]; \
        BF[ni_ * 2 + 1] = *(const bf16x8*)&bT[brow + ((G) * 128 + ni_ * 16) * 64 + swz1]; \
    } } while (0)

// one C-quadrant: 16 MFMA (4 Mfrag x 2 Nfrag x 2 kk), kk ascending = K order
#define MFMA16(H, G, BF) do { \
    __builtin_amdgcn_s_setprio(1); \
    _Pragma("unroll") for (int mi_ = 0; mi_ < 4; ++mi_) \
    _Pragma("unroll") for (int ni_ = 0; ni_ < 2; ++ni_) \
    _Pragma("unroll") for (int kk_ = 0; kk_ < 2; ++kk_) \
        acc[(H) * 4 + mi_][(G) * 2 + ni_] = __builtin_amdgcn_mfma_f32_16x16x32_bf16( \
            af[mi_ * 2 + kk_], BF[ni_ * 2 + kk_], acc[(H) * 4 + mi_][(G) * 2 + ni_], 0, 0, 0); \
    __builtin_amdgcn_s_setprio(0); \
} while (0)

// One K-tile = 4 phases. Reads buf BUF, stages tile TT+1 into buf 1-BUF.
// Issue order A0',B0',B1',A1'; waits W1/W2/W4 at ends of P1/P2/P4.
// Steady state (per wave, 2 loads/half): end P1 outstanding {B1,A1,A0'}=6,
// VMW(4) retires B1 (needed in P2). end P2 {A1,A0',B0'}=6, VMW(4) retires
// A1 (needed in P3). end P4 {A0',B0',B1',A1'}=8, VMW(4) retires A0',B0'
// (needed in next P1). Never below 4 outstanding.
#define TILE(BUF, TT, PRE, W1, W2, W4) do { \
    const u16* aT = lds + (BUF) * TILEU; \
    const u16* bT = lds + 2 * TILEU + (BUF) * TILEU; \
    u16* sA = lds + (1 - (BUF)) * TILEU; \
    u16* sB = lds + 2 * TILEU + (1 - (BUF)) * TILEU; \
    const long ko = (long)((TT) + 1) * BK; \
    /* P1: stage A0' | read A0,B0 (lds half0) | mfma (M0,N0) */ \
    if (PRE) { gload_lds16(pa[0] + ko, sA + t * 8); \
               gload_lds16(pa[1] + ko, sA + 4096 + t * 8); } \
    READ_A(0); READ_B(0, bf0); \
    BAR(); LGKM0; \
    MFMA16(0, 0, bf0); \
    W1; BAR(); \
    /* P2: stage B0' | read B1 (lds half1) | mfma (M0,N1) */ \
    if (PRE) { gload_lds16(pb[0] + ko, sB + t * 8); \
               gload_lds16(pb[1] + ko, sB + 4096 + t * 8); } \
    READ_B(1, bf1); \
    BAR(); LGKM0; \
    MFMA16(0, 1, bf1); \
    W2; BAR(); \
    /* P3: stage B1' | read A1 (lds half1) | mfma (M1,N1) */ \
    if (PRE) { gload_lds16(pb[2] + ko, sB + 8192 + t * 8); \
               gload_lds16(pb[3] + ko, sB + 12288 + t * 8); } \
    READ_A(1); \
    BAR(); LGKM0; \
    MFMA16(1, 1, bf1); \
    BAR(); \
    /* P4: stage A1' | mfma (M1,N0), B0 held in regs */ \
    if (PRE) { gload_lds16(pa[2] + ko, sA + 8192 + t * 8); \
               gload_lds16(pa[3] + ko, sA + 12288 + t * 8); } \
    MFMA16(1, 0, bf0); \
    W4; BAR(); \
} while (0)

__launch_bounds__(512, 2)
__global__ void k_gemm(const u16* __restrict__ A, const u16* __restrict__ B,
                       const float* __restrict__ bias, float* __restrict__ C,
                       int M, int N, int K) {
    extern __shared__ __align__(16) u16 lds[];

    // XCD-aware swizzle: 512 blocks, 8 XCDs, 64 blocks/chunk (bijective).
    const int wg = blockIdx.x;
    const int swzb = (wg & 7) * 64 + (wg >> 3);
    const int bn = swzb & 15, bm = swzb >> 4;     // 16 N-blocks x 32 M-blocks
    const int m0 = bm * BM, n0 = bn * BN;

    const int t = threadIdx.x;
    const int wave = t >> 6, lane = t & 63;
    const int wm = wave >> 2, wn = wave & 3;      // 2 (M) x 4 (N) waves
    const int lr = lane & 15, quad = lane >> 4;

    // Staging with PHASE-PERMUTED row layout. Tile = 2048 16B-chunks; thread
    // loads chunks ci = j*512+t (j=0..3). LDS is linear in ci. LDS row
    // lrow = ci>>3 maps to global rows:
    //   A: rA = ((lrow>>6)&1)*128 + (lrow>>7)*64 + (lrow&63)
    //      (lds half0 = global rows {0..63, 128..191} = phase-H0 rows)
    //   B: rB = ((lrow>>5)&3)*64 + (lrow>>7)*32 + (lrow&31)
    //      (lds half0 = global 32-row segments {0,2,4,6} = phase-G0 rows)
    // Chunk swizzle: lds slot (ci&7) holds global chunk (ci&7)^(lrow&7).
    // Per call, global rows form whole 32/64-row blocks -> coalesced.
    const u16 *pa[4], *pb[4];
#pragma unroll
    for (int j = 0; j < 4; ++j) {
        int ci = j * 512 + t;
        int lrow = ci >> 3;
        int c = (ci & 7) ^ (lrow & 7);
        int rA = ((lrow >> 6) & 1) * 128 + (lrow >> 7) * 64 + (lrow & 63);
        int rB = ((lrow >> 5) & 3) * 64 + (lrow >> 7) * 32 + (lrow & 31);
        pa[j] = &A[(long)(m0 + rA) * K + c * 8];
        pb[j] = &B[(long)(n0 + rB) * K + c * 8];
    }

    // Fragment-read constants. All lds-row additives are multiples of 16, so
    // lds_row&7 == lr&7; chunk k of a row sits at slot k^(lr&7). Chunk for
    // kk-th K-slice = quad + kk*4. Proven 0 bank conflicts (R3 scheme).
    const int swz0 = ((quad    ) ^ (lr & 7)) * 8;
    const int swz1 = ((quad + 4) ^ (lr & 7)) * 8;
    const int arow = (wm * 64 + lr) * 64;         // + H*128*64 in READ_A
    const int brow = (wn * 32 + lr) * 64;         // + G*128*64 in READ_B

    f32x4 acc[8][4];
#pragma unroll
    for (int mi = 0; mi < 8; ++mi)
#pragma unroll
        for (int ni = 0; ni < 4; ++ni) acc[mi][ni] = 0.f;

    bf16x8 af[8], bf0[4], bf1[4];

    // Prologue: stage tile 0 in half order A0,B0,B1,A1; vmcnt(4) -> A0,B0
    // landed (B1,A1 still in flight == steady-state invariant).
    gload_lds16(pa[0], lds + t * 8);
    gload_lds16(pa[1], lds + 4096 + t * 8);
    gload_lds16(pb[0], lds + 2 * TILEU + t * 8);
    gload_lds16(pb[1], lds + 2 * TILEU + 4096 + t * 8);
    gload_lds16(pb[2], lds + 2 * TILEU + 8192 + t * 8);
    gload_lds16(pb[3], lds + 2 * TILEU + 12288 + t * 8);
    gload_lds16(pa[2], lds + 8192 + t * 8);
    gload_lds16(pa[3], lds + 12288 + t * 8);
    VMW(4); BAR();

    // K = 4096 fixed -> NT = 64 tiles: 31 unrolled pairs + tiles 62, 63.
    // Tail tile 63 (no staging): entry outstanding {B1',A1'}=4 ->
    // W1=vmcnt(2) retires B1', W2=vmcnt(0) retires A1', W4 empty.
#pragma unroll 1
    for (int tt = 0; tt < 62; tt += 2) {
        TILE(0, tt,     1, VMW(4), VMW(4), VMW(4));
        TILE(1, tt + 1, 1, VMW(4), VMW(4), VMW(4));
    }
    TILE(0, 62, 1, VMW(4), VMW(4), VMW(4));
    TILE(1, 63, 0, VMW(2), VMW(0), );

    // Epilogue: D row = quad*4 + r (m), col = lr (n); add bias, store fp32.
#pragma unroll
    for (int ni = 0; ni < 4; ++ni) {
        int gn = n0 + wn * 64 + ni * 16 + lr;
        float bv = bias[gn];
#pragma unroll
        for (int mi = 0; mi < 8; ++mi) {
            int gm = m0 + wm * 128 + mi * 16 + quad * 4;
#pragma unroll
            for (int r = 0; r < 4; ++r)
                C[(long)(gm + r) * N + gn] = acc[mi][ni][r] + bv;
        }
    }
}

extern "C" void kernel_launch(void* const* d_in, const int* in_sizes, int n_in,
                              void* d_out, int out_size, void* d_ws, size_t ws_size,
                              hipStream_t stream) {
    const float* x = (const float*)d_in[0];
    const float* c0 = (const float*)d_in[1];
    const float* c1 = (const float*)d_in[2];
    const float* c2 = (const float*)d_in[3];
    const float* bias = (const float*)d_in[4];
    float* out = (float*)d_out;

    const int Mb = 8192, Nf = 4096, Kf = 4096;
    char* ws = (char*)d_ws;
    u16* xb = (u16*)ws;                                       // 67,108,864 B
    u16* wbt = (u16*)(ws + 67108864);                         // 33,554,432 B
    float* c01 = (float*)(ws + 67108864 + 33554432);          //  2,097,152 B

    // 128 KiB dynamic LDS (> 64 KiB static limit). Idempotent, capture-safe.
    hipFuncSetAttribute(reinterpret_cast<const void*>(k_gemm),
                        hipFuncAttributeMaxDynamicSharedMemorySize, LDS_BYTES);

    k_cvt<<<dim3((Mb * Kf / 8) / 256), 256, 0, stream>>>(x, xb);
    k_c01<<<dim3(2048), 256, 0, stream>>>(c0, c1, c01);
    k_w<<<dim3(8192), 256, 0, stream>>>(c01, c2, wbt);
    k_gemm<<<dim3((Mb / BM) * (Nf / BN)), dim3(512), LDS_BYTES, stream>>>(
        xb, wbt, bias, out, Mb, Nf, Kf);
}